// Round 18
// baseline (357.566 us; speedup 1.0000x reference)
//
#include <hip/hip_runtime.h>
#include <hip/hip_bf16.h>
#include <hip/hip_fp8.h>

#define N_NODES 50000
#define E_EDGES 800000
#define D_IN    128
#define HU      256
#define H_HEADS 8
#define U_DIM   32
#define OUT_DIM 64
#define CAP     64
#define H_SCALE 32.0f
#define DEGS    16      // deg stride in ints: 1 counter per 64B line
#define NPART   8       // XCD partitions (adj build)
#define PART_N  (N_NODES / NPART)
#define ADJ_BPP 96
#define SLICE_SZ ((size_t)N_NODES * 64)   // fp8 bytes per h column-slice

typedef __attribute__((ext_vector_type(8))) short short8v;
typedef __attribute__((ext_vector_type(4))) float f32x4;
typedef unsigned short u16;
typedef unsigned char u8;
typedef __attribute__((ext_vector_type(4))) unsigned short u16x4;
typedef __attribute__((ext_vector_type(8))) unsigned short u16x8;

__device__ __forceinline__ float bf2f(u16 v) {
    return __uint_as_float(((unsigned)v) << 16);
}
__device__ __forceinline__ u16 f2b(float f) {  // RNE f32->bf16
    unsigned u = __float_as_uint(f);
    return (u16)((u + 0x7FFFu + ((u >> 16) & 1u)) >> 16);
}
__device__ __forceinline__ u8 f2fp8(float f) {  // f32 -> e4m3 (OCP), saturating
    __hip_fp8_e4m3 t(f);
    return (u8)t.__x;
}

// ---------------- adjacency build: XCD-partitioned (bucket CSR by src, u16 dst) ---
__global__ __launch_bounds__(256) void adj_fill(const int* __restrict__ edges,
                                                int* __restrict__ deg,
                                                u16* __restrict__ adj) {
    int pt = blockIdx.x & (NPART - 1);
    int bi = blockIdx.x >> 3;
    int lo = pt * PART_N, hi = lo + PART_N;
    const int4* E4 = (const int4*)edges;
    const int TOT4 = E_EDGES / 2;
    const int chunk = (TOT4 + ADJ_BPP - 1) / ADJ_BPP;
    int s = bi * chunk;
    int e = s + chunk; if (e > TOT4) e = TOT4;
    for (int i = s + (int)threadIdx.x; i < e; i += 256) {
        int4 p = E4[i];
        if (p.x >= lo && p.x < hi) {
            int sl = atomicAdd(&deg[p.x * DEGS], 1);
            if (sl < CAP) adj[(size_t)p.x * CAP + sl] = (u16)p.y;
        }
        if (p.z >= lo && p.z < hi) {
            int sl = atomicAdd(&deg[p.z * DEGS], 1);
            if (sl < CAP) adj[(size_t)p.z * CAP + sl] = (u16)p.w;
        }
    }
}

// ---------------- W -> MFMA B-fragment order (bf16) ----------------
template<int K, int N, bool GAT>
__device__ __forceinline__ void wfrag_one(const float* __restrict__ W,
                                          u16* __restrict__ Wf, int tid) {
    int j  = tid & 7;
    int l  = (tid >> 3) & 63;
    int fb = tid >> 9;
    int ks = fb % (K / 32);
    int ct = fb / (K / 32);
    int k  = ks * 32 + (l >> 4) * 8 + j;
    int n  = ct * 16 + (l & 15);
    float v = GAT ? W[(size_t)(n >> 5) * (K * 32) + k * 32 + (n & 31)]
                  : W[(size_t)k * N + n];
    Wf[tid] = f2b(v);
}

// Wa[k, n] : n<8 -> sum_u Watt[n][k][u]*a[n][u] (src); n>=8 -> dst half
__device__ __forceinline__ void wa_one(const float* __restrict__ Watt,
                                       const float* __restrict__ al,
                                       u16* __restrict__ Wfs, int tid) {
    int j  = tid & 7;
    int l  = (tid >> 3) & 63;
    int ks = tid >> 9;
    int k  = ks * 32 + (l >> 4) * 8 + j;
    int n  = l & 15;
    int hd = n & 7;
    int off = (n < 8) ? 0 : 32;
    float s = 0.f;
#pragma unroll
    for (int u = 0; u < 32; ++u)
        s += Watt[(size_t)hd * 8192 + k * 32 + u] * al[hd * 64 + off + u];
    Wfs[tid] = f2b(s);
}

// wfrag + deg zeroing (runs before adj_fill)
__global__ __launch_bounds__(256) void wfrag_all(const float* __restrict__ Wpre,
                                                 const float* __restrict__ Watt,
                                                 const float* __restrict__ aatt,
                                                 const float* __restrict__ Wout,
                                                 u16* __restrict__ wf_pre,
                                                 u16* __restrict__ wf_a0,
                                                 u16* __restrict__ wf_a1,
                                                 u16* __restrict__ wf_out,
                                                 u16* __restrict__ wfs0,
                                                 u16* __restrict__ wfs1,
                                                 int* __restrict__ deg) {
    int tid = blockIdx.x * 256 + threadIdx.x;
    for (int i = tid; i < (N_NODES * DEGS) / 4; i += 736 * 256)
        ((int4*)deg)[i] = make_int4(0, 0, 0, 0);
    if (tid < 32768)        wfrag_one<D_IN, HU, false>(Wpre, wf_pre, tid);
    else if (tid < 98304)   wfrag_one<HU, HU, true>(Watt, wf_a0, tid - 32768);
    else if (tid < 163840)  wfrag_one<HU, HU, true>(Watt + 65536, wf_a1, tid - 98304);
    else if (tid < 180224)  wfrag_one<HU, OUT_DIM, false>(Wout, wf_out, tid - 163840);
    else if (tid < 184320)  wa_one(Watt, aatt, wfs0, tid - 180224);
    else if (tid < 188416)  wa_one(Watt + 65536, aatt + 512, wfs1, tid - 184320);
}

// ---------------- MFMA GEMM: C[64 x N] = A[64 x K] * W[K x N] ----------------
// MODE 0: bf16 out, +bias, relu (pre)
// MODE 1: fp8 out (x H_SCALE) SLICE-MAJOR [4][N_NODES][64] + fused s (h)
// MODE 2: f32 out, +bias
template<int K, int N, int MT, int NT, int MODE, bool ABF16>
__global__ __launch_bounds__(256) void mfma_gemm(const void* __restrict__ Ain,
                                                 const u16* __restrict__ Wf,
                                                 const float* __restrict__ bias,
                                                 void* __restrict__ Cout,
                                                 const u16* __restrict__ wfs,
                                                 u16* __restrict__ sb,
                                                 u16* __restrict__ db) {
    constexpr int SK = K + 8;
    __shared__ __align__(16) u16 as[64 * SK];
    int t  = threadIdx.x;
    int n0 = blockIdx.x * 64;

    if (ABF16) {
        constexpr int K8 = K / 8;
        const u16x8* A8 = (const u16x8*)Ain;
        for (int i = t; i < 64 * K8; i += 256) {
            int row = i / K8, c8 = i % K8;
            u16x8 v = {0, 0, 0, 0, 0, 0, 0, 0};
            if (n0 + row < N_NODES)
                v = __builtin_nontemporal_load(&A8[(size_t)(n0 + row) * K8 + c8]);
            *(u16x8*)&as[row * SK + c8 * 8] = v;
        }
    } else {
        constexpr int K4 = K / 4;
        const f32x4* A4 = (const f32x4*)Ain;
        for (int i = t; i < 64 * K4; i += 256) {
            int row = i / K4, c4 = i % K4;
            f32x4 v = {0.f, 0.f, 0.f, 0.f};
            if (n0 + row < N_NODES)
                v = __builtin_nontemporal_load(&A4[(size_t)(n0 + row) * K4 + c4]);
            u16x4 pk;
            pk.x = f2b(v.x); pk.y = f2b(v.y); pk.z = f2b(v.z); pk.w = f2b(v.w);
            *(u16x4*)&as[row * SK + c4 * 4] = pk;
        }
    }
    __syncthreads();

    int wid = t >> 6, l = t & 63;
    constexpr int NWN = N / (NT * 16);
    int col0 = (wid % NWN) * (NT * 16);
    int row0 = (wid / NWN) * (MT * 16);

    f32x4 acc[MT][NT];
#pragma unroll
    for (int mt = 0; mt < MT; ++mt)
#pragma unroll
        for (int nt = 0; nt < NT; ++nt)
            acc[mt][nt] = (f32x4){0.f, 0.f, 0.f, 0.f};
    f32x4 accs[MT];
#pragma unroll
    for (int mt = 0; mt < MT; ++mt) accs[mt] = (f32x4){0.f, 0.f, 0.f, 0.f};

    int ar  = l & 15;
    int akb = (l >> 4) * 8;
#pragma unroll
    for (int ks = 0; ks < K / 32; ++ks) {
        short8v a[MT], b[NT];
#pragma unroll
        for (int mt = 0; mt < MT; ++mt)
            a[mt] = *(const short8v*)&as[(row0 + mt * 16 + ar) * SK + ks * 32 + akb];
#pragma unroll
        for (int nt = 0; nt < NT; ++nt)
            b[nt] = *(const short8v*)&Wf[(size_t)(((((col0 >> 4) + nt) * (K / 32)) + ks) * 64 + l) * 8];
        if (MODE == 1) {
            if (wid == 0) {
                short8v bs = *(const short8v*)&wfs[(size_t)(ks * 64 + l) * 8];
#pragma unroll
                for (int mt = 0; mt < MT; ++mt)
                    accs[mt] = __builtin_amdgcn_mfma_f32_16x16x32_bf16(a[mt], bs, accs[mt], 0, 0, 0);
            }
        }
#pragma unroll
        for (int mt = 0; mt < MT; ++mt)
#pragma unroll
            for (int nt = 0; nt < NT; ++nt)
                acc[mt][nt] = __builtin_amdgcn_mfma_f32_16x16x32_bf16(a[mt], b[nt], acc[mt][nt], 0, 0, 0);
    }

    int crow = (l >> 4) * 4, ccol = l & 15;
#pragma unroll
    for (int mt = 0; mt < MT; ++mt) {
#pragma unroll
        for (int nt = 0; nt < NT; ++nt) {
            int gc = col0 + nt * 16 + ccol;
#pragma unroll
            for (int r = 0; r < 4; ++r) {
                int gr = n0 + row0 + mt * 16 + crow + r;
                if (gr >= N_NODES) continue;
                float v = acc[mt][nt][r];
                if (MODE == 0) {
                    v += bias[gc];
                    ((u16*)Cout)[(size_t)gr * N + gc] = f2b(fmaxf(v, 0.f));
                } else if (MODE == 1) {
                    ((u8*)Cout)[(size_t)(gc >> 6) * SLICE_SZ + (size_t)gr * 64 + (gc & 63)]
                        = f2fp8(v * H_SCALE);
                } else {
                    ((float*)Cout)[(size_t)gr * N + gc] = v + bias[gc];
                }
            }
        }
    }
    if (MODE == 1) {
        if (wid == 0) {   // s columns: ccol<8 -> ssrc head ccol, else sdst head ccol-8
#pragma unroll
            for (int mt = 0; mt < MT; ++mt) {
#pragma unroll
                for (int r = 0; r < 4; ++r) {
                    int gr = n0 + mt * 16 + crow + r;
                    if (gr >= N_NODES) continue;
                    float v = accs[mt][r];
                    if (ccol < 8) sb[(size_t)gr * 8 + ccol] = f2b(v);
                    else          db[(size_t)gr * 8 + ccol - 8] = f2b(v);
                }
            }
        }
    }
}

// ---------------- fused attention aggregate + relu + residual (in-place bf16 x) ----------------
// Column-sliced: block -> (node-quad, slice c = blockIdx&3). Slice = 64 channels
// (2 heads), h slice-major [4][N][64] fp8 -> 3.2MB per slice, L2-resident on its
// XCD pair (bid%8 -> XCD round-robin). Wave = one node: lane t -> edge t (scores),
// gather loop lane t -> (edge quad t>>4, dword t&15 of 64B row). den folded into
// the gather accumulator; masked by we=0 (no branches).
__global__ __launch_bounds__(256) void agg_kernel(const u8* __restrict__ hs,
                                                  const u16* __restrict__ ssrcb,
                                                  const u16* __restrict__ sdstb,
                                                  const int* __restrict__ deg,
                                                  const u16* __restrict__ adj,
                                                  u16* __restrict__ x) {
    int t  = threadIdx.x & 63;
    int wv = threadIdx.x >> 6;
    int c  = blockIdx.x & 3;                 // column slice (heads 2c, 2c+1)
    int n  = (blockIdx.x >> 2) * 4 + wv;     // N_NODES % 4 == 0
    int dg = deg[(size_t)n * DEGS];
    dg = dg > CAP ? CAP : dg;
    int dl = (t < dg) ? (int)adj[(size_t)n * CAP + t] : 0;

    // ---- scores: lane t = edge t, both heads of this slice
    unsigned sd2 = *(const unsigned*)((const u8*)sdstb + (size_t)dl * 16 + c * 4);
    float ss0 = bf2f(ssrcb[(size_t)n * 8 + 2 * c]);
    float ss1 = bf2f(ssrcb[(size_t)n * 8 + 2 * c + 1]);
    float w0 = 0.f, w1 = 0.f;
    if (t < dg) {
        float s0 = ss0 + bf2f((u16)(sd2 & 0xFFFF));
        float s1 = ss1 + bf2f((u16)(sd2 >> 16));
        s0 = s0 > 0.f ? s0 : 0.2f * s0;
        s1 = s1 > 0.f ? s1 : 0.2f * s1;
        s0 = fminf(fmaxf(s0, -2.f), 2.f);
        s1 = fminf(fmaxf(s1, -2.f), 2.f);
        w0 = __expf(s0);
        w1 = __expf(s1);
    }

    // ---- gather loop: 4 edges per dword-gather instruction
    int eg  = t >> 4;                        // edge within quad
    int ch4 = t & 15;                        // dword index in 64B row
    const u8* hbase = hs + (size_t)c * SLICE_SZ + (size_t)ch4 * 4;
    float a0 = 0.f, a1 = 0.f, a2 = 0.f, a3 = 0.f, dacc = 0.f;
    int nq = (dg + 3) >> 2;
    for (int i = 0; i < nq; ++i) {
        int e = i * 4 + eg;                  // < 64 always; w=0 past dg
        int d = __shfl(dl, e);
        float we0 = __shfl(w0, e);
        float we1 = __shfl(w1, e);
        float we = (ch4 < 8) ? we0 : we1;    // head = (ch4*4)>>5
        unsigned hw = *(const unsigned*)(hbase + (size_t)d * 64);
        auto lo = __builtin_amdgcn_cvt_pk_f32_fp8(hw, false);
        auto hi = __builtin_amdgcn_cvt_pk_f32_fp8(hw, true);
        a0 += we * lo[0];
        a1 += we * lo[1];
        a2 += we * hi[0];
        a3 += we * hi[1];
        dacc += we;
    }

    // ---- reduce over edge quads (lane bits 4,5)
#pragma unroll
    for (int m = 16; m <= 32; m <<= 1) {
        a0 += __shfl_xor(a0, m);
        a1 += __shfl_xor(a1, m);
        a2 += __shfl_xor(a2, m);
        a3 += __shfl_xor(a3, m);
        dacc += __shfl_xor(dacc, m);
    }

    if (t < 16) {   // lane t -> channels c*64 + t*4 .. +3 (den = dacc, head t>>3)
        float inv = dg > 0 ? (1.f / dacc) * (1.f / H_SCALE) : 0.f;
        size_t xo = (size_t)n * HU + c * 64 + t * 4;
        u16x4 xv = __builtin_nontemporal_load((const u16x4*)(x + xo));
        u16x4 o;
        o.x = f2b(fmaxf(a0 * inv, 0.f) + bf2f(xv.x));
        o.y = f2b(fmaxf(a1 * inv, 0.f) + bf2f(xv.y));
        o.z = f2b(fmaxf(a2 * inv, 0.f) + bf2f(xv.z));
        o.w = f2b(fmaxf(a3 * inv, 0.f) + bf2f(xv.w));
        __builtin_nontemporal_store(o, (u16x4*)(x + xo));
    }
}

extern "C" void kernel_launch(void* const* d_in, const int* in_sizes, int n_in,
                              void* d_out, int out_size, void* d_ws, size_t ws_size,
                              hipStream_t stream) {
    const float* ns   = (const float*)d_in[0];
    const int*   edges= (const int*)d_in[1];
    const float* Wpre = (const float*)d_in[2];
    const float* bpre = (const float*)d_in[3];
    const float* Watt = (const float*)d_in[4];
    const float* aatt = (const float*)d_in[5];
    const float* Wout = (const float*)d_in[6];
    const float* bout = (const float*)d_in[7];
    float* out = (float*)d_out;

    char* p = (char*)d_ws;
    u16* xA = (u16*)p;               p += (size_t)N_NODES * HU * 2;
    u8* h = (u8*)p;                  p += (size_t)N_NODES * HU;   // [4][N][64] slice-major
    u16* ssrcb = (u16*)p;            p += (size_t)N_NODES * H_HEADS * 2;
    u16* sdstb = (u16*)p;            p += (size_t)N_NODES * H_HEADS * 2;
    int* deg = (int*)p;              p += (size_t)N_NODES * DEGS * 4;
    u16* adj = (u16*)p;              p += (size_t)N_NODES * CAP * 2;
    u16* wf_pre  = (u16*)p;          p += (size_t)D_IN * HU * 2;
    u16* wf_att0 = (u16*)p;          p += (size_t)HU * HU * 2;
    u16* wf_att1 = (u16*)p;          p += (size_t)HU * HU * 2;
    u16* wf_out  = (u16*)p;          p += (size_t)HU * OUT_DIM * 2;
    u16* wfs0 = (u16*)p;             p += (size_t)4096 * 2;
    u16* wfs1 = (u16*)p;             p += (size_t)4096 * 2;

    // 1) weight repack + deg zeroing
    wfrag_all<<<736, 256, 0, stream>>>(Wpre, Watt, aatt, Wout,
                                       wf_pre, wf_att0, wf_att1, wf_out, wfs0, wfs1, deg);

    // 2) XCD-partitioned adjacency build
    adj_fill<<<NPART * ADJ_BPP, 256, 0, stream>>>(edges, deg, adj);

    const int GB = (N_NODES + 63) / 64;   // 782
    mfma_gemm<D_IN, HU, 4, 4, 0, false><<<GB, 256, 0, stream>>>(
        ns, wf_pre, bpre, xA, nullptr, nullptr, nullptr);

    u16* wf_att[2] = {wf_att0, wf_att1};
    u16* wfs[2] = {wfs0, wfs1};
    for (int l = 0; l < 2; ++l) {
        mfma_gemm<HU, HU, 4, 4, 1, true><<<GB, 256, 0, stream>>>(
            xA, wf_att[l], nullptr, h, wfs[l], ssrcb, sdstb);
        agg_kernel<<<N_NODES, 256, 0, stream>>>(h, ssrcb, sdstb, deg, adj, xA);
    }

    mfma_gemm<HU, OUT_DIM, 1, 4, 2, true><<<GB, 256, 0, stream>>>(
        xA, wf_out, bout, out, nullptr, nullptr, nullptr);
}

// Round 19
// 224.368 us; speedup vs baseline: 1.5937x; 1.5937x over previous
//
#include <hip/hip_runtime.h>
#include <hip/hip_bf16.h>
#include <hip/hip_fp8.h>

#define N_NODES 50000
#define E_EDGES 800000
#define D_IN    128
#define HU      256
#define H_HEADS 8
#define U_DIM   32
#define OUT_DIM 64
#define CAP     64
#define H_SCALE 32.0f
#define DEGS    16      // deg stride in ints: 1 counter per 64B line
#define NPART   8       // XCD partitions (adj build)
#define PART_N  (N_NODES / NPART)
#define ADJ_BPP 96

typedef __attribute__((ext_vector_type(8))) short short8v;
typedef __attribute__((ext_vector_type(4))) float f32x4;
typedef unsigned short u16;
typedef unsigned char u8;
typedef __attribute__((ext_vector_type(4))) unsigned short u16x4;
typedef __attribute__((ext_vector_type(8))) unsigned short u16x8;

__device__ __forceinline__ float bf2f(u16 v) {
    return __uint_as_float(((unsigned)v) << 16);
}
__device__ __forceinline__ u16 f2b(float f) {  // RNE f32->bf16
    unsigned u = __float_as_uint(f);
    return (u16)((u + 0x7FFFu + ((u >> 16) & 1u)) >> 16);
}
__device__ __forceinline__ u8 f2fp8(float f) {  // f32 -> e4m3 (OCP), saturating
    __hip_fp8_e4m3 t(f);
    return (u8)t.__x;
}

// ---------------- adjacency build: XCD-partitioned (bucket CSR by src, u16 dst) ---
// pt = blockIdx&7 -> partition's blocks land on one XCD (round-robin dispatch);
// adj/deg lines XCD-private -> L2-local atomics, no cross-XCD ping-pong.
__global__ __launch_bounds__(256) void adj_fill(const int* __restrict__ edges,
                                                int* __restrict__ deg,
                                                u16* __restrict__ adj) {
    int pt = blockIdx.x & (NPART - 1);
    int bi = blockIdx.x >> 3;
    int lo = pt * PART_N, hi = lo + PART_N;
    const int4* E4 = (const int4*)edges;
    const int TOT4 = E_EDGES / 2;
    const int chunk = (TOT4 + ADJ_BPP - 1) / ADJ_BPP;
    int s = bi * chunk;
    int e = s + chunk; if (e > TOT4) e = TOT4;
    for (int i = s + (int)threadIdx.x; i < e; i += 256) {
        int4 p = E4[i];
        if (p.x >= lo && p.x < hi) {
            int sl = atomicAdd(&deg[p.x * DEGS], 1);
            if (sl < CAP) adj[(size_t)p.x * CAP + sl] = (u16)p.y;
        }
        if (p.z >= lo && p.z < hi) {
            int sl = atomicAdd(&deg[p.z * DEGS], 1);
            if (sl < CAP) adj[(size_t)p.z * CAP + sl] = (u16)p.w;
        }
    }
}

// ---------------- W -> MFMA B-fragment order (bf16) ----------------
template<int K, int N, bool GAT>
__device__ __forceinline__ void wfrag_one(const float* __restrict__ W,
                                          u16* __restrict__ Wf, int tid) {
    int j  = tid & 7;
    int l  = (tid >> 3) & 63;
    int fb = tid >> 9;
    int ks = fb % (K / 32);
    int ct = fb / (K / 32);
    int k  = ks * 32 + (l >> 4) * 8 + j;
    int n  = ct * 16 + (l & 15);
    float v = GAT ? W[(size_t)(n >> 5) * (K * 32) + k * 32 + (n & 31)]
                  : W[(size_t)k * N + n];
    Wf[tid] = f2b(v);
}

// Wa[k, n] : n<8 -> sum_u Watt[n][k][u]*a[n][u] (src); n>=8 -> dst half
__device__ __forceinline__ void wa_one(const float* __restrict__ Watt,
                                       const float* __restrict__ al,
                                       u16* __restrict__ Wfs, int tid) {
    int j  = tid & 7;
    int l  = (tid >> 3) & 63;
    int ks = tid >> 9;
    int k  = ks * 32 + (l >> 4) * 8 + j;
    int n  = l & 15;
    int hd = n & 7;
    int off = (n < 8) ? 0 : 32;
    float s = 0.f;
#pragma unroll
    for (int u = 0; u < 32; ++u)
        s += Watt[(size_t)hd * 8192 + k * 32 + u] * al[hd * 64 + off + u];
    Wfs[tid] = f2b(s);
}

// wfrag + deg zeroing (runs before adj_fill)
__global__ __launch_bounds__(256) void wfrag_all(const float* __restrict__ Wpre,
                                                 const float* __restrict__ Watt,
                                                 const float* __restrict__ aatt,
                                                 const float* __restrict__ Wout,
                                                 u16* __restrict__ wf_pre,
                                                 u16* __restrict__ wf_a0,
                                                 u16* __restrict__ wf_a1,
                                                 u16* __restrict__ wf_out,
                                                 u16* __restrict__ wfs0,
                                                 u16* __restrict__ wfs1,
                                                 int* __restrict__ deg) {
    int tid = blockIdx.x * 256 + threadIdx.x;
    for (int i = tid; i < (N_NODES * DEGS) / 4; i += 736 * 256)
        ((int4*)deg)[i] = make_int4(0, 0, 0, 0);
    if (tid < 32768)        wfrag_one<D_IN, HU, false>(Wpre, wf_pre, tid);
    else if (tid < 98304)   wfrag_one<HU, HU, true>(Watt, wf_a0, tid - 32768);
    else if (tid < 163840)  wfrag_one<HU, HU, true>(Watt + 65536, wf_a1, tid - 98304);
    else if (tid < 180224)  wfrag_one<HU, OUT_DIM, false>(Wout, wf_out, tid - 163840);
    else if (tid < 184320)  wa_one(Watt, aatt, wfs0, tid - 180224);
    else if (tid < 188416)  wa_one(Watt + 65536, aatt + 512, wfs1, tid - 184320);
}

// ---------------- MFMA GEMM: C[64 x N] = A[64 x K] * W[K x N] ----------------
// MODE 0: bf16 out, +bias, relu (pre)  MODE 1: fp8 out (x H_SCALE) + fused s (h)
// MODE 2: f32 out, +bias
template<int K, int N, int MT, int NT, int MODE, bool ABF16>
__global__ __launch_bounds__(256) void mfma_gemm(const void* __restrict__ Ain,
                                                 const u16* __restrict__ Wf,
                                                 const float* __restrict__ bias,
                                                 void* __restrict__ Cout,
                                                 const u16* __restrict__ wfs,
                                                 u16* __restrict__ sb,
                                                 u16* __restrict__ db) {
    constexpr int SK = K + 8;
    __shared__ __align__(16) u16 as[64 * SK];
    int t  = threadIdx.x;
    int n0 = blockIdx.x * 64;

    if (ABF16) {
        constexpr int K8 = K / 8;
        const u16x8* A8 = (const u16x8*)Ain;
        for (int i = t; i < 64 * K8; i += 256) {
            int row = i / K8, c8 = i % K8;
            u16x8 v = {0, 0, 0, 0, 0, 0, 0, 0};
            if (n0 + row < N_NODES)
                v = __builtin_nontemporal_load(&A8[(size_t)(n0 + row) * K8 + c8]);
            *(u16x8*)&as[row * SK + c8 * 8] = v;
        }
    } else {
        constexpr int K4 = K / 4;
        const f32x4* A4 = (const f32x4*)Ain;
        for (int i = t; i < 64 * K4; i += 256) {
            int row = i / K4, c4 = i % K4;
            f32x4 v = {0.f, 0.f, 0.f, 0.f};
            if (n0 + row < N_NODES)
                v = __builtin_nontemporal_load(&A4[(size_t)(n0 + row) * K4 + c4]);
            u16x4 pk;
            pk.x = f2b(v.x); pk.y = f2b(v.y); pk.z = f2b(v.z); pk.w = f2b(v.w);
            *(u16x4*)&as[row * SK + c4 * 4] = pk;
        }
    }
    __syncthreads();

    int wid = t >> 6, l = t & 63;
    constexpr int NWN = N / (NT * 16);
    int col0 = (wid % NWN) * (NT * 16);
    int row0 = (wid / NWN) * (MT * 16);

    f32x4 acc[MT][NT];
#pragma unroll
    for (int mt = 0; mt < MT; ++mt)
#pragma unroll
        for (int nt = 0; nt < NT; ++nt)
            acc[mt][nt] = (f32x4){0.f, 0.f, 0.f, 0.f};
    f32x4 accs[MT];
#pragma unroll
    for (int mt = 0; mt < MT; ++mt) accs[mt] = (f32x4){0.f, 0.f, 0.f, 0.f};

    int ar  = l & 15;
    int akb = (l >> 4) * 8;
#pragma unroll
    for (int ks = 0; ks < K / 32; ++ks) {
        short8v a[MT], b[NT];
#pragma unroll
        for (int mt = 0; mt < MT; ++mt)
            a[mt] = *(const short8v*)&as[(row0 + mt * 16 + ar) * SK + ks * 32 + akb];
#pragma unroll
        for (int nt = 0; nt < NT; ++nt)
            b[nt] = *(const short8v*)&Wf[(size_t)(((((col0 >> 4) + nt) * (K / 32)) + ks) * 64 + l) * 8];
        if (MODE == 1) {
            if (wid == 0) {
                short8v bs = *(const short8v*)&wfs[(size_t)(ks * 64 + l) * 8];
#pragma unroll
                for (int mt = 0; mt < MT; ++mt)
                    accs[mt] = __builtin_amdgcn_mfma_f32_16x16x32_bf16(a[mt], bs, accs[mt], 0, 0, 0);
            }
        }
#pragma unroll
        for (int mt = 0; mt < MT; ++mt)
#pragma unroll
            for (int nt = 0; nt < NT; ++nt)
                acc[mt][nt] = __builtin_amdgcn_mfma_f32_16x16x32_bf16(a[mt], b[nt], acc[mt][nt], 0, 0, 0);
    }

    int crow = (l >> 4) * 4, ccol = l & 15;
#pragma unroll
    for (int mt = 0; mt < MT; ++mt) {
#pragma unroll
        for (int nt = 0; nt < NT; ++nt) {
            int gc = col0 + nt * 16 + ccol;
#pragma unroll
            for (int r = 0; r < 4; ++r) {
                int gr = n0 + row0 + mt * 16 + crow + r;
                if (gr >= N_NODES) continue;
                float v = acc[mt][nt][r];
                if (MODE == 0) {
                    v += bias[gc];
                    ((u16*)Cout)[(size_t)gr * N + gc] = f2b(fmaxf(v, 0.f));
                } else if (MODE == 1) {
                    ((u8*)Cout)[(size_t)gr * N + gc] = f2fp8(v * H_SCALE);
                } else {
                    ((float*)Cout)[(size_t)gr * N + gc] = v + bias[gc];
                }
            }
        }
    }
    if (MODE == 1) {
        if (wid == 0) {   // s columns: ccol<8 -> ssrc head ccol, else sdst head ccol-8
#pragma unroll
            for (int mt = 0; mt < MT; ++mt) {
#pragma unroll
                for (int r = 0; r < 4; ++r) {
                    int gr = n0 + mt * 16 + crow + r;
                    if (gr >= N_NODES) continue;
                    float v = accs[mt][r];
                    if (ccol < 8) sb[(size_t)gr * 8 + ccol] = f2b(v);
                    else          db[(size_t)gr * 8 + ccol - 8] = f2b(v);
                }
            }
        }
    }
}

// ---------------- fused attention aggregate + relu + residual (in-place bf16 x) ----------------
// 4 waves/block = 4 nodes. fp8 h rows (256B), wide-gather 16B/lane (4 edges/instr).
// Fast path (dg<=32): ALL h-gathers issued up-front (<=8 independent VMEM in flight),
// score phase (exp/LDS) computes under gather latency, then register decode.
__global__ __launch_bounds__(256) void agg_kernel(const u8* __restrict__ hb,
                                                  const u16* __restrict__ ssrcb,
                                                  const u16* __restrict__ sdstb,
                                                  const int* __restrict__ deg,
                                                  const u16* __restrict__ adj,
                                                  u16* __restrict__ x) {
    __shared__ u16 sd_lds[4][64 * 8];   // per-wave [edge][head] bf16
    int t  = threadIdx.x & 63;
    int wv = threadIdx.x >> 6;
    int n  = blockIdx.x * 4 + wv;       // N_NODES % 4 == 0
    int dg = deg[(size_t)n * DEGS];
    dg = dg > CAP ? CAP : dg;
    int dl = (t < dg) ? (int)__builtin_nontemporal_load(&adj[(size_t)n * CAP + t]) : 0;
    // preload sdst rows for all edges: ONE 16B/lane gather
    u16x8 sdrow = *(const u16x8*)(sdstb + (size_t)dl * 8);
    *(u16x8*)&sd_lds[wv][t * 8] = sdrow;
    __syncthreads();

    int hd8 = t & 7;                       // score-phase head
    float ss_s = bf2f(ssrcb[(size_t)n * 8 + hd8]);
    int q   = t >> 4;                      // gather-phase edge-quad
    int sub = t & 15;                      // 16B chunk within row
    int hdg = sub >> 1;                    // gather-phase head

    float a[16];
#pragma unroll
    for (int i = 0; i < 16; ++i) a[i] = 0.f;
    float den_part = 0.f;

    if (dg <= 32) {
        // ---- 1) issue all h-gathers back-to-back (independent; addresses from dl only)
        int nq = (dg + 3) >> 2;
        uint4 hv0, hv1, hv2, hv3, hv4, hv5, hv6, hv7;
        {
            uint4* hvp[8] = {&hv0, &hv1, &hv2, &hv3, &hv4, &hv5, &hv6, &hv7};
#pragma unroll
            for (int i = 0; i < 8; ++i) {
                if (i < nq) {                               // wave-uniform
                    int d = __shfl(dl, i * 4 + q);          // lanes >= dg hold 0 (safe)
                    *hvp[i] = *(const uint4*)(hb + (size_t)d * HU + sub * 16);
                }
            }
        }
        // ---- 2) score phase overlaps gather latency: 4 groups x (8 edges x 8 heads)
        float w[4];
#pragma unroll
        for (int sg = 0; sg < 4; ++sg) {
            int eidx = sg * 8 + (t >> 3);
            float ww = 0.f;
            if (eidx < dg) {
                float sc = ss_s + bf2f(sd_lds[wv][eidx * 8 + hd8]);
                sc = sc > 0.f ? sc : 0.2f * sc;            // leaky_relu(0.2)
                sc = fminf(fmaxf(sc, -2.f), 2.f);          // clip
                ww = __expf(sc);
            }
            w[sg] = ww;
            den_part += ww;
        }
        // ---- 3) decode from registers
        const uint4* hvp[8] = {&hv0, &hv1, &hv2, &hv3, &hv4, &hv5, &hv6, &hv7};
#pragma unroll
        for (int i = 0; i < 8; ++i) {
            if (i < nq) {
                int e4 = i * 4 + q;
                float we = __shfl(w[i >> 1], ((e4 & 7) << 3) | hdg);
                if (e4 < dg) {
                    uint4 hvv = *hvp[i];
#pragma unroll
                    for (int k = 0; k < 4; ++k) {
                        unsigned dw = (&hvv.x)[k];
                        auto lo = __builtin_amdgcn_cvt_pk_f32_fp8(dw, false);
                        auto hi = __builtin_amdgcn_cvt_pk_f32_fp8(dw, true);
                        a[4 * k + 0] += we * lo[0];
                        a[4 * k + 1] += we * lo[1];
                        a[4 * k + 2] += we * hi[0];
                        a[4 * k + 3] += we * hi[1];
                    }
                }
            }
        }
    } else {
        // ---- fallback: rare high-degree nodes (dg in (32,64])
        for (int base = 0; base < dg; base += 8) {
            int eidx = base + (t >> 3);
            float w = 0.f;
            if (eidx < dg) {
                float sc = ss_s + bf2f(sd_lds[wv][eidx * 8 + hd8]);
                sc = sc > 0.f ? sc : 0.2f * sc;
                sc = fminf(fmaxf(sc, -2.f), 2.f);
                w = __expf(sc);
            }
            den_part += w;
#pragma unroll
            for (int g = 0; g < 2; ++g) {
                int e4 = base + g * 4 + q;
                int d  = __shfl(dl, e4);
                float we = __shfl(w, ((g * 4 + q) << 3) | hdg);
                if (e4 < dg) {
                    uint4 hvv = *(const uint4*)(hb + (size_t)d * HU + sub * 16);
#pragma unroll
                    for (int k = 0; k < 4; ++k) {
                        unsigned dw = (&hvv.x)[k];
                        auto lo = __builtin_amdgcn_cvt_pk_f32_fp8(dw, false);
                        auto hi = __builtin_amdgcn_cvt_pk_f32_fp8(dw, true);
                        a[4 * k + 0] += we * lo[0];
                        a[4 * k + 1] += we * lo[1];
                        a[4 * k + 2] += we * hi[0];
                        a[4 * k + 3] += we * hi[1];
                    }
                }
            }
        }
    }

    // den: sum over lane bits 3-5 -> every lane holds full den for head t&7
    den_part += __shfl_xor(den_part, 8);
    den_part += __shfl_xor(den_part, 16);
    den_part += __shfl_xor(den_part, 32);
    // accumulators: sum over edge-quads (lane bits 4-5)
#pragma unroll
    for (int i = 0; i < 16; ++i) {
        a[i] += __shfl_xor(a[i], 16);
        a[i] += __shfl_xor(a[i], 32);
    }

    if (q == 0) {   // lanes 0-15: channels sub*16..+15
        float den = __shfl(den_part, hdg);           // lane hdg holds head hdg
        float inv = dg > 0 ? (1.f / den) * (1.f / H_SCALE) : 0.f;
        size_t xo = (size_t)n * HU + sub * 16;
        u16x8 xv0 = __builtin_nontemporal_load((const u16x8*)(x + xo));
        u16x8 xv1 = __builtin_nontemporal_load((const u16x8*)(x + xo + 8));
        u16x8 o0, o1;
#pragma unroll
        for (int i = 0; i < 8; ++i) {
            o0[i] = f2b(fmaxf(a[i] * inv, 0.f) + bf2f((u16)xv0[i]));
            o1[i] = f2b(fmaxf(a[8 + i] * inv, 0.f) + bf2f((u16)xv1[i]));
        }
        __builtin_nontemporal_store(o0, (u16x8*)(x + xo));
        __builtin_nontemporal_store(o1, (u16x8*)(x + xo + 8));
    }
}

extern "C" void kernel_launch(void* const* d_in, const int* in_sizes, int n_in,
                              void* d_out, int out_size, void* d_ws, size_t ws_size,
                              hipStream_t stream) {
    const float* ns   = (const float*)d_in[0];
    const int*   edges= (const int*)d_in[1];
    const float* Wpre = (const float*)d_in[2];
    const float* bpre = (const float*)d_in[3];
    const float* Watt = (const float*)d_in[4];
    const float* aatt = (const float*)d_in[5];
    const float* Wout = (const float*)d_in[6];
    const float* bout = (const float*)d_in[7];
    float* out = (float*)d_out;

    char* p = (char*)d_ws;
    u16* xA = (u16*)p;               p += (size_t)N_NODES * HU * 2;
    u8* h = (u8*)p;                  p += (size_t)N_NODES * HU;   // [N][256] fp8 row-major
    u16* ssrcb = (u16*)p;            p += (size_t)N_NODES * H_HEADS * 2;
    u16* sdstb = (u16*)p;            p += (size_t)N_NODES * H_HEADS * 2;
    int* deg = (int*)p;              p += (size_t)N_NODES * DEGS * 4;
    u16* adj = (u16*)p;              p += (size_t)N_NODES * CAP * 2;
    u16* wf_pre  = (u16*)p;          p += (size_t)D_IN * HU * 2;
    u16* wf_att0 = (u16*)p;          p += (size_t)HU * HU * 2;
    u16* wf_att1 = (u16*)p;          p += (size_t)HU * HU * 2;
    u16* wf_out  = (u16*)p;          p += (size_t)HU * OUT_DIM * 2;
    u16* wfs0 = (u16*)p;             p += (size_t)4096 * 2;
    u16* wfs1 = (u16*)p;             p += (size_t)4096 * 2;

    // 1) weight repack + deg zeroing
    wfrag_all<<<736, 256, 0, stream>>>(Wpre, Watt, aatt, Wout,
                                       wf_pre, wf_att0, wf_att1, wf_out, wfs0, wfs1, deg);

    // 2) XCD-partitioned adjacency build
    adj_fill<<<NPART * ADJ_BPP, 256, 0, stream>>>(edges, deg, adj);

    const int GB = (N_NODES + 63) / 64;   // 782
    mfma_gemm<D_IN, HU, 4, 4, 0, false><<<GB, 256, 0, stream>>>(
        ns, wf_pre, bpre, xA, nullptr, nullptr, nullptr);

    u16* wf_att[2] = {wf_att0, wf_att1};
    u16* wfs[2] = {wfs0, wfs1};
    for (int l = 0; l < 2; ++l) {
        mfma_gemm<HU, HU, 4, 4, 1, true><<<GB, 256, 0, stream>>>(
            xA, wf_att[l], nullptr, h, wfs[l], ssrcb, sdstb);
        agg_kernel<<<(N_NODES / 4), 256, 0, stream>>>(h, ssrcb, sdstb, deg, adj, xA);
    }

    mfma_gemm<HU, OUT_DIM, 1, 4, 2, true><<<GB, 256, 0, stream>>>(
        xA, wf_out, bout, out, nullptr, nullptr, nullptr);
}